// Round 1
// baseline (145.615 us; speedup 1.0000x reference)
//
#include <hip/hip_runtime.h>
#include <math.h>

#define N_NODES 100000
#define N_EDGES 1600000
#define IN_DIM  128
#define OUT_DIM 32
#define LEAKY   0.2f

// ---------------- Kernel A: z = X @ W, s_src = z@a_src, s_dst = z@a_dst ----
// Block = 256 threads = 8 groups of 32 lanes. Each group computes one row's
// 32 output columns. W staged in LDS (16 KB), X rows staged via float4.
__global__ __launch_bounds__(256) void gemm_s_kernel(
    const float* __restrict__ X, const float* __restrict__ W,
    const float* __restrict__ a_src, const float* __restrict__ a_dst,
    float* __restrict__ z, float* __restrict__ ssrc, float* __restrict__ sdst)
{
    __shared__ float Wl[IN_DIM * OUT_DIM];   // 16 KB
    __shared__ float Xl[8][IN_DIM];          // 4 KB
    __shared__ float al[2][OUT_DIM];

    const int t = threadIdx.x;
    for (int i = t; i < IN_DIM * OUT_DIM; i += 256) Wl[i] = W[i];
    if (t < OUT_DIM) { al[0][t] = a_src[t]; al[1][t] = a_dst[t]; }

    const int rowBase = blockIdx.x * 8;

    // cooperative load: 8 rows x 128 floats = 1024 floats = 256 x float4
    {
        const int idx = t * 4;
        const int r = idx / IN_DIM;
        const int k = idx % IN_DIM;
        const int row = rowBase + r;
        if (row < N_NODES) {
            const float4 v = *reinterpret_cast<const float4*>(&X[(size_t)row * IN_DIM + k]);
            Xl[r][k + 0] = v.x; Xl[r][k + 1] = v.y;
            Xl[r][k + 2] = v.z; Xl[r][k + 3] = v.w;
        }
    }
    __syncthreads();

    const int g = t >> 5;        // row within block
    const int c = t & 31;        // output column
    const int row = rowBase + g;
    if (row >= N_NODES) return;

    float acc = 0.f;
    #pragma unroll 8
    for (int k = 0; k < IN_DIM; ++k)
        acc = fmaf(Xl[g][k], Wl[k * OUT_DIM + c], acc);

    z[(size_t)row * OUT_DIM + c] = acc;

    // 32-lane reductions for the two attention scalars
    float ps = acc * al[0][c];
    float pd = acc * al[1][c];
    #pragma unroll
    for (int m = 16; m >= 1; m >>= 1) {
        ps += __shfl_xor(ps, m, 64);
        pd += __shfl_xor(pd, m, 64);
    }
    if (c == 0) { ssrc[row] = ps; sdst[row] = pd; }
}

// ---------------- Kernel B: CSR offsets from sorted dst ----------------
// off[n] = first edge index with dst >= n ; off[N_NODES] = N_EDGES.
__global__ __launch_bounds__(256) void offsets_kernel(
    const int* __restrict__ dst, int* __restrict__ off)
{
    const int e = blockIdx.x * blockDim.x + threadIdx.x;
    if (e >= N_EDGES) return;
    const int d = dst[e];
    const int dprev = (e == 0) ? -1 : dst[e - 1];
    for (int n = dprev + 1; n <= d; ++n) off[n] = e;
    if (e == N_EDGES - 1) {
        for (int n = d + 1; n <= N_NODES; ++n) off[n] = N_EDGES;
    }
}

// ---------------- Kernel C: fused softmax + aggregation ----------------
// One 32-lane group per dst node; lane = output channel. Registers hold the
// running numerator (32-vec) and denominator; softmax without max-subtraction
// (scores ~ N(0,2), exp never overflows fp32). Single plain store per node.
__global__ __launch_bounds__(256) void agg_kernel(
    const float* __restrict__ z, const float* __restrict__ ssrc,
    const float* __restrict__ sdst, const int* __restrict__ src,
    const int* __restrict__ off, float* __restrict__ out)
{
    const int t = threadIdx.x;
    const int g = t >> 5;
    const int c = t & 31;
    const int n = blockIdx.x * 8 + g;
    if (n >= N_NODES) return;

    const int lo = off[n];
    const int hi = off[n + 1];
    const float sd = sdst[n];

    float acc = 0.f;
    float den = 0.f;
    for (int e = lo; e < hi; ++e) {
        const int s = src[e];
        float x = ssrc[s] + sd;
        x = (x > 0.f) ? x : LEAKY * x;
        const float v = __expf(x);
        acc = fmaf(v, z[(size_t)s * OUT_DIM + c], acc);
        den += v;
    }
    const float r = (den > 0.f) ? (acc / den) : 0.f;
    out[(size_t)n * OUT_DIM + c] = fmaxf(r, 0.f);
}

// ---------------- launch ----------------
extern "C" void kernel_launch(void* const* d_in, const int* in_sizes, int n_in,
                              void* d_out, int out_size, void* d_ws, size_t ws_size,
                              hipStream_t stream) {
    const float* X     = (const float*)d_in[0];
    const float* W     = (const float*)d_in[1];
    const float* a_src = (const float*)d_in[2];
    const float* a_dst = (const float*)d_in[3];
    const int*   src   = (const int*)d_in[4];
    const int*   dst   = (const int*)d_in[5];
    float* out = (float*)d_out;

    // workspace partition
    char* ws = (char*)d_ws;
    float* z    = (float*)ws;                                  ws += (size_t)N_NODES * OUT_DIM * sizeof(float);
    float* ssrc = (float*)ws;                                  ws += (size_t)N_NODES * sizeof(float);
    float* sdst = (float*)ws;                                  ws += (size_t)N_NODES * sizeof(float);
    int*   off  = (int*)ws;                                    ws += (size_t)(N_NODES + 1) * sizeof(int);

    gemm_s_kernel<<<(N_NODES + 7) / 8, 256, 0, stream>>>(X, W, a_src, a_dst, z, ssrc, sdst);
    offsets_kernel<<<(N_EDGES + 255) / 256, 256, 0, stream>>>(dst, off);
    agg_kernel<<<(N_NODES + 7) / 8, 256, 0, stream>>>(z, ssrc, sdst, src, off, out);
}

// Round 2
// 77.262 us; speedup vs baseline: 1.8847x; 1.8847x over previous
//
#include <hip/hip_runtime.h>
#include <math.h>

#define N_NODES 100000
#define N_EDGES 1600000
#define IN_DIM  128
#define OUT_DIM 32
#define LEAKY   0.2f

// ---------------- Kernel A: z = X @ W, s_src = z@a_src, s_dst = z@a_dst ----
// Block 256 threads; tile = 128 rows x 32 cols; each thread computes a 4x4
// register tile (rows 4*tr.., cols 4*tc..). X staged k-major (transposed) in
// LDS with an XOR swizzle so both the b128 reads and writes behave; W staged
// row-major (conflict-free b128 reads). 2 ds_read_b128 feed 16 FMAs.
__global__ __launch_bounds__(256) void gemm_s_kernel(
    const float* __restrict__ X, const float* __restrict__ W,
    const float* __restrict__ a_src, const float* __restrict__ a_dst,
    float* __restrict__ z, float* __restrict__ ssrc, float* __restrict__ sdst)
{
    __shared__ float Wl[IN_DIM][OUT_DIM];   // 16 KB
    __shared__ float Xt[64][132];           // 33.8 KB, k-major half tile (swizzled)

    const int t  = threadIdx.x;
    const int tr = t >> 3;                  // 0..31 : row group (4 rows each)
    const int tc = t & 7;                   // 0..7  : col group (4 cols each)
    const int rowBase = blockIdx.x * 128;

    for (int i = t; i < IN_DIM * OUT_DIM; i += 256)
        ((float*)Wl)[i] = W[i];

    const float4 as4 = *reinterpret_cast<const float4*>(&a_src[tc << 2]);
    const float4 ad4 = *reinterpret_cast<const float4*>(&a_dst[tc << 2]);

    float acc[4][4];
    #pragma unroll
    for (int i = 0; i < 4; ++i)
        #pragma unroll
        for (int j = 0; j < 4; ++j) acc[i][j] = 0.f;

    for (int h = 0; h < 2; ++h) {
        const int k0 = h << 6;
        __syncthreads();
        // stage 128 rows x 64 k, transposed + swizzled: 8 float4 per thread
        #pragma unroll
        for (int i = 0; i < 8; ++i) {
            const int vidx = i * 256 + t;          // 0..2047
            const int row  = vidx >> 4;
            const int k4   = (vidx & 15) << 2;
            const int grow = rowBase + row;
            float4 v = make_float4(0.f, 0.f, 0.f, 0.f);
            if (grow < N_NODES)
                v = *reinterpret_cast<const float4*>(&X[(size_t)grow * IN_DIM + k0 + k4]);
            Xt[k4 + 0][row ^ (((k4 + 0) & 7) << 2)] = v.x;
            Xt[k4 + 1][row ^ (((k4 + 1) & 7) << 2)] = v.y;
            Xt[k4 + 2][row ^ (((k4 + 2) & 7) << 2)] = v.z;
            Xt[k4 + 3][row ^ (((k4 + 3) & 7) << 2)] = v.w;
        }
        __syncthreads();
        #pragma unroll 8
        for (int k = 0; k < 64; ++k) {
            const float4 xv = *reinterpret_cast<const float4*>(
                &Xt[k][(tr << 2) ^ ((k & 7) << 2)]);
            const float4 wv = *reinterpret_cast<const float4*>(
                &Wl[k0 + k][tc << 2]);
            acc[0][0] = fmaf(xv.x, wv.x, acc[0][0]);
            acc[0][1] = fmaf(xv.x, wv.y, acc[0][1]);
            acc[0][2] = fmaf(xv.x, wv.z, acc[0][2]);
            acc[0][3] = fmaf(xv.x, wv.w, acc[0][3]);
            acc[1][0] = fmaf(xv.y, wv.x, acc[1][0]);
            acc[1][1] = fmaf(xv.y, wv.y, acc[1][1]);
            acc[1][2] = fmaf(xv.y, wv.z, acc[1][2]);
            acc[1][3] = fmaf(xv.y, wv.w, acc[1][3]);
            acc[2][0] = fmaf(xv.z, wv.x, acc[2][0]);
            acc[2][1] = fmaf(xv.z, wv.y, acc[2][1]);
            acc[2][2] = fmaf(xv.z, wv.z, acc[2][2]);
            acc[2][3] = fmaf(xv.z, wv.w, acc[2][3]);
            acc[3][0] = fmaf(xv.w, wv.x, acc[3][0]);
            acc[3][1] = fmaf(xv.w, wv.y, acc[3][1]);
            acc[3][2] = fmaf(xv.w, wv.z, acc[3][2]);
            acc[3][3] = fmaf(xv.w, wv.w, acc[3][3]);
        }
    }

    #pragma unroll
    for (int i = 0; i < 4; ++i) {
        const int row = rowBase + (tr << 2) + i;
        if (row >= N_NODES) continue;          // uniform across the 8 tc lanes
        float4 zr = make_float4(acc[i][0], acc[i][1], acc[i][2], acc[i][3]);
        *reinterpret_cast<float4*>(&z[(size_t)row * OUT_DIM + (tc << 2)]) = zr;
        float ps = acc[i][0]*as4.x + acc[i][1]*as4.y + acc[i][2]*as4.z + acc[i][3]*as4.w;
        float pd = acc[i][0]*ad4.x + acc[i][1]*ad4.y + acc[i][2]*ad4.z + acc[i][3]*ad4.w;
        #pragma unroll
        for (int m = 1; m <= 4; m <<= 1) {
            ps += __shfl_xor(ps, m, 64);
            pd += __shfl_xor(pd, m, 64);
        }
        if (tc == 0) { ssrc[row] = ps; sdst[row] = pd; }
    }
}

// ---------------- Kernel B: CSR offsets from sorted dst ----------------
__global__ __launch_bounds__(256) void offsets_kernel(
    const int* __restrict__ dst, int* __restrict__ off)
{
    const int e = blockIdx.x * blockDim.x + threadIdx.x;
    if (e >= N_EDGES) return;
    const int d = dst[e];
    const int dprev = (e == 0) ? -1 : dst[e - 1];
    for (int n = dprev + 1; n <= d; ++n) off[n] = e;
    if (e == N_EDGES - 1) {
        for (int n = d + 1; n <= N_NODES; ++n) off[n] = N_EDGES;
    }
}

// ---------------- Kernel C: fused softmax + aggregation ----------------
// One 32-lane group per dst node, lane = output channel. Edges processed in
// chunks of 32: coalesced src load + lane-parallel exp, (s,v) staged in LDS,
// inner loop = broadcast ds_read + 4 independent 128B z-row gathers in flight.
__global__ __launch_bounds__(256) void agg_kernel(
    const float* __restrict__ z, const float* __restrict__ ssrc,
    const float* __restrict__ sdst, const int* __restrict__ src,
    const int* __restrict__ off, float* __restrict__ out)
{
    __shared__ float2 sv[8][32];
    const int t = threadIdx.x;
    const int g = t >> 5;
    const int c = t & 31;
    const int n = blockIdx.x * 8 + g;
    if (n >= N_NODES) return;

    const int lo = off[n];
    const int hi = off[n + 1];
    const float sd = sdst[n];

    float acc = 0.f;
    float den = 0.f;

    for (int base = lo; base < hi; base += 32) {
        int s = 0;
        float v = 0.f;
        const int e = base + c;
        if (e < hi) {
            s = src[e];
            float x = ssrc[s] + sd;
            x = (x > 0.f) ? x : LEAKY * x;
            v = __expf(x);
        }
        den += v;
        sv[g][c] = make_float2(__int_as_float(s), v);
        const int cnt = min(32, hi - base);
        int j = 0;
        for (; j + 4 <= cnt; j += 4) {
            const float4 q01 = *reinterpret_cast<const float4*>(&sv[g][j]);
            const float4 q23 = *reinterpret_cast<const float4*>(&sv[g][j + 2]);
            const int s0 = __float_as_int(q01.x), s1 = __float_as_int(q01.z);
            const int s2 = __float_as_int(q23.x), s3 = __float_as_int(q23.z);
            const float z0 = z[s0 * OUT_DIM + c];
            const float z1 = z[s1 * OUT_DIM + c];
            const float z2 = z[s2 * OUT_DIM + c];
            const float z3 = z[s3 * OUT_DIM + c];
            acc = fmaf(q01.y, z0, acc);
            acc = fmaf(q01.w, z1, acc);
            acc = fmaf(q23.y, z2, acc);
            acc = fmaf(q23.w, z3, acc);
        }
        for (; j < cnt; ++j) {
            const float2 p = sv[g][j];
            acc = fmaf(p.y, z[__float_as_int(p.x) * OUT_DIM + c], acc);
        }
    }

    #pragma unroll
    for (int m = 16; m >= 1; m >>= 1) den += __shfl_xor(den, m, 64);

    const float r = (den > 0.f) ? (acc / den) : 0.f;
    out[n * OUT_DIM + c] = fmaxf(r, 0.f);
}

// ---------------- launch ----------------
extern "C" void kernel_launch(void* const* d_in, const int* in_sizes, int n_in,
                              void* d_out, int out_size, void* d_ws, size_t ws_size,
                              hipStream_t stream) {
    const float* X     = (const float*)d_in[0];
    const float* W     = (const float*)d_in[1];
    const float* a_src = (const float*)d_in[2];
    const float* a_dst = (const float*)d_in[3];
    const int*   src   = (const int*)d_in[4];
    const int*   dst   = (const int*)d_in[5];
    float* out = (float*)d_out;

    char* ws = (char*)d_ws;
    float* z    = (float*)ws;   ws += (size_t)N_NODES * OUT_DIM * sizeof(float);
    float* ssrc = (float*)ws;   ws += (size_t)N_NODES * sizeof(float);
    float* sdst = (float*)ws;   ws += (size_t)N_NODES * sizeof(float);
    int*   off  = (int*)ws;     ws += (size_t)(N_NODES + 1) * sizeof(int);

    gemm_s_kernel<<<(N_NODES + 127) / 128, 256, 0, stream>>>(X, W, a_src, a_dst, z, ssrc, sdst);
    offsets_kernel<<<(N_EDGES + 255) / 256, 256, 0, stream>>>(dst, off);
    agg_kernel<<<(N_NODES + 7) / 8, 256, 0, stream>>>(z, ssrc, sdst, src, off, out);
}

// Round 3
// 72.634 us; speedup vs baseline: 2.0048x; 1.0637x over previous
//
#include <hip/hip_runtime.h>
#include <math.h>

#define N_NODES 100000
#define N_EDGES 1600000
#define IN_DIM  128
#define OUT_DIM 32
#define LEAKY   0.2f

// ---------------- Kernel A: z = X @ W, s_src = z@a_src, s_dst = z@a_dst ----
// 256 threads, tile = 128 rows x 32 cols, per-thread 4x4 register tile.
// X staged ROW-MAJOR in LDS per 64-wide K-half with a float4-slot rotation
// swizzle: slot = (k4 + tr) & 15. Hand-checked bank math: staging writes
// cover all 8 bank-groups (8 phases = floor for 1024B), compute reads give 8
// distinct bank-groups across the wave's 8 tr values (8-way tc broadcast).
// W padded [128][36]: reads (4k+4tc)%32 -> 8 groups, conflict-free.
__global__ __launch_bounds__(256) void gemm_s_kernel(
    const float* __restrict__ X, const float* __restrict__ W,
    const float* __restrict__ a_src, const float* __restrict__ a_dst,
    float* __restrict__ z, float* __restrict__ ssrc, float* __restrict__ sdst)
{
    __shared__ float Wl[IN_DIM][36];   // 18.4 KB
    __shared__ float Xs[128][64];      // 32 KB (one K-half, swizzled)

    const int t  = threadIdx.x;
    const int tr = t >> 3;             // 0..31 : 4-row group
    const int tc = t & 7;              // 0..7  : 4-col group
    const int rowBase = blockIdx.x * 128;

    for (int i = t; i < IN_DIM * OUT_DIM; i += 256)
        Wl[i >> 5][i & 31] = W[i];

    const float4 as4 = *reinterpret_cast<const float4*>(&a_src[tc << 2]);
    const float4 ad4 = *reinterpret_cast<const float4*>(&a_dst[tc << 2]);

    float acc[4][4];
    #pragma unroll
    for (int i = 0; i < 4; ++i)
        #pragma unroll
        for (int j = 0; j < 4; ++j) acc[i][j] = 0.f;

    for (int h = 0; h < 2; ++h) {
        const int k0 = h << 6;
        __syncthreads();
        // stage 128 rows x 64 floats (2048 float4, 8 per thread), coalesced
        #pragma unroll
        for (int i = 0; i < 8; ++i) {
            const int vidx = (i << 8) + t;
            const int row  = vidx >> 4;        // 0..127
            const int j    = vidx & 15;        // float4 slot along k
            const int grow = rowBase + row;
            float4 v = make_float4(0.f, 0.f, 0.f, 0.f);
            if (grow < N_NODES)
                v = *reinterpret_cast<const float4*>(&X[(size_t)grow * IN_DIM + k0 + (j << 2)]);
            const int slot = (j + (row >> 2)) & 15;
            *reinterpret_cast<float4*>(&Xs[row][slot << 2]) = v;
        }
        __syncthreads();

        #pragma unroll 4
        for (int kk = 0; kk < 64; kk += 4) {
            const int j = kk >> 2;
            const int slot = (j + tr) & 15;    // row>>2 == tr for all 4 rows
            float4 xv[4];
            #pragma unroll
            for (int i = 0; i < 4; ++i)
                xv[i] = *reinterpret_cast<const float4*>(&Xs[(tr << 2) + i][slot << 2]);
            #pragma unroll
            for (int q = 0; q < 4; ++q) {
                const float4 wv = *reinterpret_cast<const float4*>(&Wl[k0 + kk + q][tc << 2]);
                const float xq0 = (q == 0) ? xv[0].x : (q == 1) ? xv[0].y : (q == 2) ? xv[0].z : xv[0].w;
                const float xq1 = (q == 0) ? xv[1].x : (q == 1) ? xv[1].y : (q == 2) ? xv[1].z : xv[1].w;
                const float xq2 = (q == 0) ? xv[2].x : (q == 1) ? xv[2].y : (q == 2) ? xv[2].z : xv[2].w;
                const float xq3 = (q == 0) ? xv[3].x : (q == 1) ? xv[3].y : (q == 2) ? xv[3].z : xv[3].w;
                acc[0][0] = fmaf(xq0, wv.x, acc[0][0]);
                acc[0][1] = fmaf(xq0, wv.y, acc[0][1]);
                acc[0][2] = fmaf(xq0, wv.z, acc[0][2]);
                acc[0][3] = fmaf(xq0, wv.w, acc[0][3]);
                acc[1][0] = fmaf(xq1, wv.x, acc[1][0]);
                acc[1][1] = fmaf(xq1, wv.y, acc[1][1]);
                acc[1][2] = fmaf(xq1, wv.z, acc[1][2]);
                acc[1][3] = fmaf(xq1, wv.w, acc[1][3]);
                acc[2][0] = fmaf(xq2, wv.x, acc[2][0]);
                acc[2][1] = fmaf(xq2, wv.y, acc[2][1]);
                acc[2][2] = fmaf(xq2, wv.z, acc[2][2]);
                acc[2][3] = fmaf(xq2, wv.w, acc[2][3]);
                acc[3][0] = fmaf(xq3, wv.x, acc[3][0]);
                acc[3][1] = fmaf(xq3, wv.y, acc[3][1]);
                acc[3][2] = fmaf(xq3, wv.z, acc[3][2]);
                acc[3][3] = fmaf(xq3, wv.w, acc[3][3]);
            }
        }
    }

    #pragma unroll
    for (int i = 0; i < 4; ++i) {
        const int row = rowBase + (tr << 2) + i;
        if (row >= N_NODES) continue;          // uniform across the 8 tc lanes
        float4 zr = make_float4(acc[i][0], acc[i][1], acc[i][2], acc[i][3]);
        *reinterpret_cast<float4*>(&z[(size_t)row * OUT_DIM + (tc << 2)]) = zr;
        float ps = acc[i][0]*as4.x + acc[i][1]*as4.y + acc[i][2]*as4.z + acc[i][3]*as4.w;
        float pd = acc[i][0]*ad4.x + acc[i][1]*ad4.y + acc[i][2]*ad4.z + acc[i][3]*ad4.w;
        #pragma unroll
        for (int m = 1; m <= 4; m <<= 1) {
            ps += __shfl_xor(ps, m, 64);
            pd += __shfl_xor(pd, m, 64);
        }
        if (tc == 0) { ssrc[row] = ps; sdst[row] = pd; }
    }
}

// ---------------- Kernel B: CSR offsets from sorted dst ----------------
__global__ __launch_bounds__(256) void offsets_kernel(
    const int* __restrict__ dst, int* __restrict__ off)
{
    const int e = blockIdx.x * blockDim.x + threadIdx.x;
    if (e >= N_EDGES) return;
    const int d = dst[e];
    const int dprev = (e == 0) ? -1 : dst[e - 1];
    for (int n = dprev + 1; n <= d; ++n) off[n] = e;
    if (e == N_EDGES - 1) {
        for (int n = d + 1; n <= N_NODES; ++n) off[n] = N_EDGES;
    }
}

// ---------------- Kernel C: fused softmax + aggregation ----------------
// One 32-lane group per dst node, lane = output channel. 32-edge chunks:
// coalesced src load + lane-parallel exp; (s*32, v) staged in LDS; inner
// loop issues 8 INDEPENDENT z-row gathers into separate registers before
// any FMA -> 8 loads in flight per wave-group.
__global__ __launch_bounds__(256) void agg_kernel(
    const float* __restrict__ z, const float* __restrict__ ssrc,
    const float* __restrict__ sdst, const int* __restrict__ src,
    const int* __restrict__ off, float* __restrict__ out)
{
    __shared__ float2 sv[8][32];
    const int t = threadIdx.x;
    const int g = t >> 5;
    const int c = t & 31;
    const int n = blockIdx.x * 8 + g;
    if (n >= N_NODES) return;

    const int lo = off[n];
    const int hi = off[n + 1];
    const float sd = sdst[n];

    float acc = 0.f;
    float den = 0.f;

    for (int base = lo; base < hi; base += 32) {
        int srow = 0;
        float v = 0.f;
        const int e = base + c;
        if (e < hi) {
            const int s = src[e];
            srow = s * OUT_DIM;                 // pre-scaled row offset
            float x = ssrc[s] + sd;
            x = (x > 0.f) ? x : LEAKY * x;
            v = __expf(x);
        }
        den += v;
        sv[g][c] = make_float2(__int_as_float(srow), v);
        const int cnt = min(32, hi - base);
        int j = 0;
        for (; j + 8 <= cnt; j += 8) {
            const float4 q0 = *reinterpret_cast<const float4*>(&sv[g][j + 0]);
            const float4 q1 = *reinterpret_cast<const float4*>(&sv[g][j + 2]);
            const float4 q2 = *reinterpret_cast<const float4*>(&sv[g][j + 4]);
            const float4 q3 = *reinterpret_cast<const float4*>(&sv[g][j + 6]);
            const float z0 = z[__float_as_int(q0.x) + c];
            const float z1 = z[__float_as_int(q0.z) + c];
            const float z2 = z[__float_as_int(q1.x) + c];
            const float z3 = z[__float_as_int(q1.z) + c];
            const float z4 = z[__float_as_int(q2.x) + c];
            const float z5 = z[__float_as_int(q2.z) + c];
            const float z6 = z[__float_as_int(q3.x) + c];
            const float z7 = z[__float_as_int(q3.z) + c];
            acc = fmaf(q0.y, z0, acc);
            acc = fmaf(q0.w, z1, acc);
            acc = fmaf(q1.y, z2, acc);
            acc = fmaf(q1.w, z3, acc);
            acc = fmaf(q2.y, z4, acc);
            acc = fmaf(q2.w, z5, acc);
            acc = fmaf(q3.y, z6, acc);
            acc = fmaf(q3.w, z7, acc);
        }
        for (; j + 4 <= cnt; j += 4) {
            const float4 q0 = *reinterpret_cast<const float4*>(&sv[g][j + 0]);
            const float4 q1 = *reinterpret_cast<const float4*>(&sv[g][j + 2]);
            const float z0 = z[__float_as_int(q0.x) + c];
            const float z1 = z[__float_as_int(q0.z) + c];
            const float z2 = z[__float_as_int(q1.x) + c];
            const float z3 = z[__float_as_int(q1.z) + c];
            acc = fmaf(q0.y, z0, acc);
            acc = fmaf(q0.w, z1, acc);
            acc = fmaf(q1.y, z2, acc);
            acc = fmaf(q1.w, z3, acc);
        }
        for (; j < cnt; ++j) {
            const float2 p = sv[g][j];
            acc = fmaf(p.y, z[__float_as_int(p.x) + c], acc);
        }
    }

    #pragma unroll
    for (int m = 16; m >= 1; m >>= 1) den += __shfl_xor(den, m, 64);

    const float r = (den > 0.f) ? (acc / den) : 0.f;
    out[n * OUT_DIM + c] = fmaxf(r, 0.f);
}

// ---------------- launch ----------------
extern "C" void kernel_launch(void* const* d_in, const int* in_sizes, int n_in,
                              void* d_out, int out_size, void* d_ws, size_t ws_size,
                              hipStream_t stream) {
    const float* X     = (const float*)d_in[0];
    const float* W     = (const float*)d_in[1];
    const float* a_src = (const float*)d_in[2];
    const float* a_dst = (const float*)d_in[3];
    const int*   src   = (const int*)d_in[4];
    const int*   dst   = (const int*)d_in[5];
    float* out = (float*)d_out;

    char* ws = (char*)d_ws;
    float* z    = (float*)ws;   ws += (size_t)N_NODES * OUT_DIM * sizeof(float);
    float* ssrc = (float*)ws;   ws += (size_t)N_NODES * sizeof(float);
    float* sdst = (float*)ws;   ws += (size_t)N_NODES * sizeof(float);
    int*   off  = (int*)ws;     ws += (size_t)(N_NODES + 1) * sizeof(int);

    gemm_s_kernel<<<(N_NODES + 127) / 128, 256, 0, stream>>>(X, W, a_src, a_dst, z, ssrc, sdst);
    offsets_kernel<<<(N_EDGES + 255) / 256, 256, 0, stream>>>(dst, off);
    agg_kernel<<<(N_NODES + 7) / 8, 256, 0, stream>>>(z, ssrc, sdst, src, off, out);
}